// Round 5
// baseline (497.138 us; speedup 1.0000x reference)
//
#include <hip/hip_runtime.h>
#include <hip/hip_bf16.h>
#include <math.h>

#define DIM 2048
#define NH 32
#define NKV 8
#define HD 64
#define SEQ 2048
#define BATCH 2
#define MTOT (BATCH*SEQ)          // 4096
#define QKV_N ((NH + 2*NKV)*HD)   // 3072
#define QSCALE 0.18033688011112042f   // log2(e)/8

typedef __bf16 bf16x8 __attribute__((ext_vector_type(8)));
typedef float f32x4 __attribute__((ext_vector_type(4)));

#if __has_builtin(__builtin_amdgcn_exp2f)
#define EXP2F __builtin_amdgcn_exp2f
#else
#define EXP2F exp2f
#endif

__device__ __forceinline__ void gld_lds16(const void* g, void* l) {
  __builtin_amdgcn_global_load_lds((__attribute__((address_space(1))) void*)g,
                                   (__attribute__((address_space(3))) void*)l,
                                   16, 0, 0);
}

// ---------------- elementwise: fp32 -> bf16 ----------------
__global__ void cvt_x_kernel(const float* __restrict__ src, __hip_bfloat16* __restrict__ dst, int n4) {
  int i = blockIdx.x * 256 + threadIdx.x;
  if (i >= n4) return;
  float4 v = ((const float4*)src)[i];
  union { __hip_bfloat16 h[4]; uint2 u; } t;
  t.h[0] = __float2bfloat16(v.x); t.h[1] = __float2bfloat16(v.y);
  t.h[2] = __float2bfloat16(v.z); t.h[3] = __float2bfloat16(v.w);
  ((uint2*)dst)[i] = t.u;
}

// ---------------- transpose + convert: src R x C fp32 -> dst C x R bf16 ----------------
__global__ void transpose_cvt_kernel(const float* __restrict__ src, __hip_bfloat16* __restrict__ dst,
                                     int R, int C) {
  __shared__ float tile[32][33];
  int c0 = blockIdx.x * 32, r0 = blockIdx.y * 32;
  int tx = threadIdx.x & 31, ty = threadIdx.x >> 5;
  #pragma unroll
  for (int i = ty; i < 32; i += 8)
    tile[i][tx] = src[(size_t)(r0 + i) * C + c0 + tx];
  __syncthreads();
  #pragma unroll
  for (int i = ty; i < 32; i += 8)
    dst[(size_t)(c0 + i) * R + r0 + tx] = __float2bfloat16(tile[tx][i]);
}

// ---------------- barrier-free register-direct GEMM core ----------------
// One wave per block (64 threads). Wave owns a 64x64 tile, acc 4x4 of 16x16x32 MFMA.
// A[M][K], Bt[N][K] both row-major along K: fragment = 16B/lane global load, no LDS.
// Software-pipelined one K-tile ahead; no barriers anywhere in the loop.
__device__ __forceinline__ void gemm_rr_core(const __hip_bfloat16* __restrict__ A,
                                             const __hip_bfloat16* __restrict__ Bt,
                                             int m0, int n0, int K, f32x4 (&acc)[4][4]) {
  const int lane = threadIdx.x & 63, ln = lane & 15, quad = lane >> 4;
  const __hip_bfloat16* pa[4];
  const __hip_bfloat16* pb[4];
  #pragma unroll
  for (int i = 0; i < 4; i++)
    pa[i] = A + (size_t)(m0 + i * 16 + ln) * K + quad * 8;
  #pragma unroll
  for (int j = 0; j < 4; j++)
    pb[j] = Bt + (size_t)(n0 + j * 16 + ln) * K + quad * 8;

  bf16x8 af[4], bf[4], an[4], bn[4];
  #pragma unroll
  for (int i = 0; i < 4; i++) af[i] = *(const bf16x8*)(pa[i]);
  #pragma unroll
  for (int j = 0; j < 4; j++) bf[j] = *(const bf16x8*)(pb[j]);

  for (int k0 = 32; k0 < K; k0 += 32) {
    #pragma unroll
    for (int i = 0; i < 4; i++) an[i] = *(const bf16x8*)(pa[i] + k0);
    #pragma unroll
    for (int j = 0; j < 4; j++) bn[j] = *(const bf16x8*)(pb[j] + k0);
    #pragma unroll
    for (int i = 0; i < 4; i++)
      #pragma unroll
      for (int j = 0; j < 4; j++)
        acc[i][j] = __builtin_amdgcn_mfma_f32_16x16x32_bf16(af[i], bf[j], acc[i][j], 0, 0, 0);
    #pragma unroll
    for (int i = 0; i < 4; i++) af[i] = an[i];
    #pragma unroll
    for (int j = 0; j < 4; j++) bf[j] = bn[j];
  }
  #pragma unroll
  for (int i = 0; i < 4; i++)
    #pragma unroll
    for (int j = 0; j < 4; j++)
      acc[i][j] = __builtin_amdgcn_mfma_f32_16x16x32_bf16(af[i], bf[j], acc[i][j], 0, 0, 0);
}

// ---------------- QKV GEMM + fused RoPE + head-major scatter ----------------
// grid 3072 = 64 by-tiles x 48 bx-tiles. XCD-banded: xcd = id&7 owns A rows
// [xcd*512, +512) (2 MB, L2-resident); bx sweeps all 48 panels (B via L3).
__global__ __launch_bounds__(64, 3) void gemm_qkv_rope_kernel(const __hip_bfloat16* __restrict__ A,
                                                              const __hip_bfloat16* __restrict__ Bt,
                                                              const float* __restrict__ freqs,
                                                              __hip_bfloat16* __restrict__ Qb,
                                                              __hip_bfloat16* __restrict__ Kb,
                                                              __hip_bfloat16* __restrict__ Vb) {
  const int id = blockIdx.x;
  const int xcd = id & 7, s = id >> 3;          // s in [0,384)
  const int by = xcd * 8 + (s & 7);             // [0,64)
  const int bx = s >> 3;                        // [0,48)
  const int m0 = by * 64, n0 = bx * 64;
  f32x4 acc[4][4] = {};
  gemm_rr_core(A, Bt, m0, n0, DIM, acc);

  const int lane = threadIdx.x & 63, ln = lane & 15, quad = lane >> 4;
  // n-tile is exactly one head: region uniform per block
  #pragma unroll
  for (int i = 0; i < 4; i++) {
    #pragma unroll
    for (int j = 0; j < 4; j++) {
      const int d = j * 16 + ln;                // [0,64)
      #pragma unroll
      for (int r = 0; r < 4; r++) {
        const int m = m0 + i * 16 + quad * 4 + r;
        const int bb = m >> 11, ss = m & 2047;
        float v = acc[i][j][r];
        if (bx >= 40) {          // V head bx-40
          Vb[((size_t)(bb * NKV + (bx - 40)) * SEQ + ss) * HD + d] = __float2bfloat16(v);
        } else {
          float p = __shfl_xor(v, 1);
          const float2 fc = *(const float2*)&freqs[ss * 64 + (d & ~1)];
          float o = (d & 1) ? (v * fc.x + p * fc.y) : (v * fc.x - p * fc.y);
          if (bx < 32)           // Q head bx
            Qb[((size_t)(bb * NH + bx) * SEQ + ss) * HD + d] = __float2bfloat16(o * QSCALE);
          else                   // K head bx-32
            Kb[((size_t)(bb * NKV + (bx - 32)) * SEQ + ss) * HD + d] = __float2bfloat16(o);
        }
      }
    }
  }
}

// ---------------- WO GEMM, fp32 out ----------------
// grid 2048 = 64 by x 32 bx; same XCD banding.
__global__ __launch_bounds__(64, 3) void gemm_wo_kernel(const __hip_bfloat16* __restrict__ A,
                                                        const __hip_bfloat16* __restrict__ Bt,
                                                        float* __restrict__ C) {
  const int id = blockIdx.x;
  const int xcd = id & 7, s = id >> 3;          // s in [0,256)
  const int by = xcd * 8 + (s & 7);             // [0,64)
  const int bx = s >> 3;                        // [0,32)
  const int m0 = by * 64, n0 = bx * 64;
  f32x4 acc[4][4] = {};
  gemm_rr_core(A, Bt, m0, n0, DIM, acc);

  const int lane = threadIdx.x & 63, ln = lane & 15, quad = lane >> 4;
  #pragma unroll
  for (int i = 0; i < 4; i++) {
    const int r0 = m0 + i * 16 + quad * 4;
    #pragma unroll
    for (int j = 0; j < 4; j++) {
      const int cc = n0 + j * 16 + ln;
      #pragma unroll
      for (int r = 0; r < 4; r++)
        C[(size_t)(r0 + r) * DIM + cc] = acc[i][j][r];
    }
  }
}

// ---------------- flash-style causal GQA attention (r4 version, unchanged) ----------------
__global__ __launch_bounds__(256, 3) void attn_kernel(const __hip_bfloat16* __restrict__ Q,
                                                      const __hip_bfloat16* __restrict__ Kg,
                                                      const __hip_bfloat16* __restrict__ Vg,
                                                      __hip_bfloat16* __restrict__ O) {
  __shared__ __hip_bfloat16 Ks[128 * 64];     // chunk-swizzled: phys = kv*8 + (dBlk ^ (kv&7))
  __shared__ __hip_bfloat16 Vs[64 * 136];     // [d][s ^ ((d>>4&3)<<4)], stride 136
  __shared__ __hip_bfloat16 Ps[4][32 * 72];   // per-wave P, col ^ (quad<<4), stride 72
  const int id = blockIdx.x;
  const int xcd = id & 7, slot = id >> 3;
  const int cmb = xcd * 2 + (slot >> 6);      // 0..15
  const int b = cmb >> 3, kvh = cmb & 7;
  const int s_ = slot & 63;
  const int t = 15 - (s_ >> 2);               // big tiles first per XCD
  const int h = kvh * 4 + (s_ & 3);
  const int tid = threadIdx.x, w = tid >> 6, lane = tid & 63, ln = lane & 15, quad = lane >> 4;
  const size_t qbase = (size_t)(b * NH + h) * SEQ * HD;
  const size_t kbase = (size_t)(b * NKV + kvh) * SEQ * HD;

  const __hip_bfloat16* Kgl = Kg + kbase + (size_t)(tid >> 3) * 64 + (size_t)(((tid & 7) ^ ((tid >> 3) & 7)) * 8);
  const int vrow = tid >> 2, vcb = (tid & 3) * 16, vsw = (tid & 3) << 4;
  const int psw = ((ln >> 2) & 3) << 4;

  const int qgw = t * 128 + w * 32;
  bf16x8 qf[2][2];
  #pragma unroll
  for (int f = 0; f < 2; f++)
    #pragma unroll
    for (int kt = 0; kt < 2; kt++)
      qf[f][kt] = *(const bf16x8*)(Q + qbase + (size_t)(qgw + f * 16 + ln) * HD + kt * 32 + quad * 8);
  f32x4 Oacc[2][4] = {};
  float lrow[2][4] = {};
  union { unsigned short u[8]; bf16x8 v; } onesu;
  #pragma unroll
  for (int i = 0; i < 8; i++) onesu.u[i] = 0x3F80;
  const bf16x8 ones = onesu.v;

  uint4 vd[2][2];
  #pragma unroll
  for (int bt = 0; bt < 2; bt++)
    #pragma unroll
    for (int cc = 0; cc < 2; cc++)
      vd[bt][cc] = *(const uint4*)(Vg + kbase + (size_t)(bt * 64 + vrow) * HD + vcb + cc * 8);

  for (int j = 0; j <= t; j++) {
    #pragma unroll
    for (int c = 0; c < 4; c++)
      gld_lds16(Kgl + (size_t)j * 8192 + c * 2048, &Ks[c * 2048 + w * 512]);
    #pragma unroll
    for (int bt = 0; bt < 2; bt++)
      #pragma unroll
      for (int cc = 0; cc < 2; cc++) {
        const __hip_bfloat16* vp = (const __hip_bfloat16*)&vd[bt][cc];
        const int col = vcb + cc * 8;
        const int sr = (bt * 64 + vrow) ^ vsw;
        #pragma unroll
        for (int e = 0; e < 8; e++)
          Vs[(col + e) * 136 + sr] = vp[e];
      }
    __syncthreads();
    if (j < t) {
      #pragma unroll
      for (int bt = 0; bt < 2; bt++)
        #pragma unroll
        for (int cc = 0; cc < 2; cc++)
          vd[bt][cc] = *(const uint4*)(Vg + kbase + (size_t)((j + 1) * 128 + bt * 64 + vrow) * HD + vcb + cc * 8);
    }
    const bool lastIter = (j == t);
    #pragma unroll
    for (int s2 = 0; s2 < 2; s2++) {
      if (lastIter && s2 * 64 > w * 32 + 31) continue;
      bf16x8 kf[4][2];
      #pragma unroll
      for (int nt = 0; nt < 4; nt++)
        #pragma unroll
        for (int kt = 0; kt < 2; kt++) {
          const int kv = s2 * 64 + nt * 16 + ln;
          kf[nt][kt] = *(const bf16x8*)&Ks[(kv * 8 + ((kt * 4 + quad) ^ (ln & 7))) * 8];
        }
      #pragma unroll
      for (int f = 0; f < 2; f++) {
        if (lastIter && s2 * 64 > w * 32 + f * 16 + 15) continue;
        f32x4 sf[4];
        #pragma unroll
        for (int nt = 0; nt < 4; nt++) {
          f32x4 s = {};
          s = __builtin_amdgcn_mfma_f32_16x16x32_bf16(qf[f][0], kf[nt][0], s, 0, 0, 0);
          s = __builtin_amdgcn_mfma_f32_16x16x32_bf16(qf[f][1], kf[nt][1], s, 0, 0, 0);
          sf[nt] = s;
        }
        if (lastIter && s2 * 64 + 63 > w * 32 + f * 16) {
          const int qr = w * 32 + f * 16 + quad * 4;
          #pragma unroll
          for (int nt = 0; nt < 4; nt++) {
            const int kg = s2 * 64 + nt * 16 + ln;
            #pragma unroll
            for (int r = 0; r < 4; r++)
              if (kg > qr + r) sf[nt][r] = -1.0e38f;
          }
        }
        #pragma unroll
        for (int nt = 0; nt < 4; nt++)
          #pragma unroll
          for (int r = 0; r < 4; r++)
            Ps[w][(f * 16 + quad * 4 + r) * 72 + ((nt * 16 + ln) ^ (quad << 4))] =
                __float2bfloat16(EXP2F(sf[nt][r]));
      }
      #pragma unroll
      for (int f = 0; f < 2; f++) {
        if (lastIter && s2 * 64 > w * 32 + f * 16 + 15) continue;
        f32x4 ls = {};
        #pragma unroll
        for (int kt = 0; kt < 2; kt++) {
          bf16x8 pf = *(const bf16x8*)&Ps[w][(f * 16 + ln) * 72 + ((kt * 32 + quad * 8) ^ psw)];
          ls = __builtin_amdgcn_mfma_f32_16x16x32_bf16(pf, ones, ls, 0, 0, 0);
          #pragma unroll
          for (int dt = 0; dt < 4; dt++) {
            bf16x8 vf = *(const bf16x8*)&Vs[(dt * 16 + ln) * 136 + s2 * 64 + ((kt * 32 + quad * 8) ^ (dt << 4))];
            Oacc[f][dt] = __builtin_amdgcn_mfma_f32_16x16x32_bf16(pf, vf, Oacc[f][dt], 0, 0, 0);
          }
        }
        #pragma unroll
        for (int r = 0; r < 4; r++) lrow[f][r] += ls[r];
      }
    }
    __syncthreads();
  }
  #pragma unroll
  for (int f = 0; f < 2; f++) {
    const int so = qgw + f * 16 + quad * 4;
    #pragma unroll
    for (int r = 0; r < 4; r++) {
      const float inv = 1.0f / lrow[f][r];
      #pragma unroll
      for (int dt = 0; dt < 4; dt++)
        O[((size_t)(b * SEQ) + so + r) * DIM + h * HD + dt * 16 + ln] =
            __float2bfloat16(Oacc[f][dt][r] * inv);
    }
  }
}

extern "C" void kernel_launch(void* const* d_in, const int* in_sizes, int n_in,
                              void* d_out, int out_size, void* d_ws, size_t ws_size,
                              hipStream_t stream) {
  const float* x     = (const float*)d_in[0];
  const float* freqs = (const float*)d_in[1];
  const float* wqkv  = (const float*)d_in[2];
  const float* wo    = (const float*)d_in[3];
  float* out = (float*)d_out;

  char* ws = (char*)d_ws;
  __hip_bfloat16* xb    = (__hip_bfloat16*)ws; ws += (size_t)MTOT * DIM * 2;
  __hip_bfloat16* wqkvT = (__hip_bfloat16*)ws; ws += (size_t)QKV_N * DIM * 2;
  __hip_bfloat16* woT   = (__hip_bfloat16*)ws; ws += (size_t)DIM * DIM * 2;
  __hip_bfloat16* Qb    = (__hip_bfloat16*)ws; ws += (size_t)BATCH * NH * SEQ * HD * 2;
  __hip_bfloat16* Kb    = (__hip_bfloat16*)ws; ws += (size_t)BATCH * NKV * SEQ * HD * 2;
  __hip_bfloat16* Vb    = (__hip_bfloat16*)ws; ws += (size_t)BATCH * NKV * SEQ * HD * 2;
  __hip_bfloat16* attnb = (__hip_bfloat16*)ws; ws += (size_t)MTOT * DIM * 2;

  cvt_x_kernel<<<(MTOT * DIM / 4 + 255) / 256, 256, 0, stream>>>(x, xb, MTOT * DIM / 4);
  transpose_cvt_kernel<<<dim3(QKV_N / 32, DIM / 32), 256, 0, stream>>>(wqkv, wqkvT, DIM, QKV_N);
  transpose_cvt_kernel<<<dim3(DIM / 32, DIM / 32), 256, 0, stream>>>(wo, woT, DIM, DIM);
  gemm_qkv_rope_kernel<<<3072, 64, 0, stream>>>(xb, wqkvT, freqs, Qb, Kb, Vb);
  attn_kernel<<<1024, 256, 0, stream>>>(Qb, Kb, Vb, attnb);
  gemm_wo_kernel<<<2048, 64, 0, stream>>>(attnb, woT, out);
}